// Round 7
// baseline (7103.135 us; speedup 1.0000x reference)
//
#include <hip/hip_runtime.h>
#include <math.h>

#define NB 512
#define SS 128
#define DD 128
#define NH 8
#define NSTEP 126

// ---------------- precompute: wtp/wmp/plcq projections (f64 inner, f32 out) ----
__global__ __launch_bounds__(128) void proj_kernel(
    const float* __restrict__ vtmax, const float* __restrict__ vm,
    const float* __restrict__ wplc, const float* __restrict__ Wupd,
    float* __restrict__ wtp, float* __restrict__ wmp, float* __restrict__ plcq)
{
  int d = threadIdx.x;
  double a = 0.0, b = 0.0, c = 0.0;
  for (int k = 0; k < DD; k++) {
    a += (double)vtmax[k] * (double)Wupd[(size_t)(DD + k) * DD + d];
    b += (double)vm[k]    * (double)Wupd[(size_t)(2 * DD + k) * DD + d];
    c += (double)wplc[k]  * (double)Wupd[(size_t)k * DD + d];
  }
  wtp[d] = (float)a; wmp[d] = (float)b; plcq[d] = (float)c;
}

// ---------------- precompute: h_hat = mean(enc,1) @ W_ctx (f64 inner, f32 out) ----
__global__ __launch_bounds__(128) void hhat_kernel(
    const float* __restrict__ enc, const float* __restrict__ Wctx,
    float* __restrict__ hh)
{
  __shared__ double mean[DD];
  int b = blockIdx.x, d = threadIdx.x;
  double s = 0.0;
  for (int j = 0; j < SS; j++) s += (double)enc[((size_t)b * SS + j) * DD + d];
  mean[d] = s * (1.0 / 128.0);
  __syncthreads();
  double a = 0.0;
  for (int k = 0; k < DD; k++) a += mean[k] * (double)Wctx[(size_t)k * DD + d];
  hh[(size_t)b * DD + d] = (float)a;
}

// ---- generic GEMM (f64 accumulate, f32 out): C = A(65536x128) @ B(128 x ncols) ----
__global__ __launch_bounds__(256) void gemm64(
    const float* __restrict__ A, const float* __restrict__ Bm, int ldb,
    float* __restrict__ C, int ldc)
{
  __shared__ float As[64][132];
  __shared__ float Bs[64][68];
  const int r0 = blockIdx.x * 64;
  const int c0 = blockIdx.y * 64;
  const int tid = threadIdx.x;
  #pragma unroll
  for (int i = 0; i < 8; i++) {
    int idx = tid + 256 * i;
    int rr = idx >> 5;
    int cc = (idx & 31) << 2;
    *(float4*)&As[rr][cc] = *(const float4*)&A[(size_t)(r0 + rr) * DD + cc];
  }
  const int trow = (tid >> 4) << 2;
  const int tcol = (tid & 15) << 2;
  double acc[4][4] = {};
  for (int kh = 0; kh < 2; kh++) {
    __syncthreads();
    #pragma unroll
    for (int i = 0; i < 4; i++) {
      int idx = tid + 256 * i;
      int rr = idx >> 4;
      int cc = (idx & 15) << 2;
      *(float4*)&Bs[rr][cc] = *(const float4*)&Bm[(size_t)(kh * 64 + rr) * ldb + c0 + cc];
    }
    __syncthreads();
    #pragma unroll 2
    for (int k2 = 0; k2 < 64; k2++) {
      int k = kh * 64 + k2;
      double a0 = (double)As[trow][k],     a1 = (double)As[trow + 1][k],
             a2 = (double)As[trow + 2][k], a3 = (double)As[trow + 3][k];
      float4 b4 = *(const float4*)&Bs[k2][tcol];
      double bx = (double)b4.x, by = (double)b4.y, bz = (double)b4.z, bw = (double)b4.w;
      acc[0][0] += a0 * bx; acc[0][1] += a0 * by; acc[0][2] += a0 * bz; acc[0][3] += a0 * bw;
      acc[1][0] += a1 * bx; acc[1][1] += a1 * by; acc[1][2] += a1 * bz; acc[1][3] += a1 * bw;
      acc[2][0] += a2 * bx; acc[2][1] += a2 * by; acc[2][2] += a2 * bz; acc[2][3] += a2 * bw;
      acc[3][0] += a3 * bx; acc[3][1] += a3 * by; acc[3][2] += a3 * bz; acc[3][3] += a3 * bw;
    }
  }
  #pragma unroll
  for (int i = 0; i < 4; i++) {
    float* cp = &C[(size_t)(r0 + trow + i) * ldc + c0 + tcol];
    cp[0] = (float)acc[i][0]; cp[1] = (float)acc[i][1];
    cp[2] = (float)acc[i][2]; cp[3] = (float)acc[i][3];
  }
}

// ---- kvl GEMM with layout-split epilogue: gK4 [b][h][j4][s]x4, gVrow [b][s][c], logKT [b][k][s]
__global__ __launch_bounds__(256) void gemm_kvl(
    const float* __restrict__ A, const float* __restrict__ Bm,
    float* __restrict__ gK4, float* __restrict__ gVrow, float* __restrict__ lKT)
{
  __shared__ float As[64][132];
  __shared__ float Bs[64][68];
  const int r0 = blockIdx.x * 64;
  const int c0 = blockIdx.y * 64;
  const int tid = threadIdx.x;
  #pragma unroll
  for (int i = 0; i < 8; i++) {
    int idx = tid + 256 * i;
    int rr = idx >> 5;
    int cc = (idx & 31) << 2;
    *(float4*)&As[rr][cc] = *(const float4*)&A[(size_t)(r0 + rr) * DD + cc];
  }
  const int trow = (tid >> 4) << 2;
  const int tcol = (tid & 15) << 2;
  double acc[4][4] = {};
  for (int kh = 0; kh < 2; kh++) {
    __syncthreads();
    #pragma unroll
    for (int i = 0; i < 4; i++) {
      int idx = tid + 256 * i;
      int rr = idx >> 4;
      int cc = (idx & 15) << 2;
      *(float4*)&Bs[rr][cc] = *(const float4*)&Bm[(size_t)(kh * 64 + rr) * 384 + c0 + cc];
    }
    __syncthreads();
    #pragma unroll 2
    for (int k2 = 0; k2 < 64; k2++) {
      int k = kh * 64 + k2;
      double a0 = (double)As[trow][k],     a1 = (double)As[trow + 1][k],
             a2 = (double)As[trow + 2][k], a3 = (double)As[trow + 3][k];
      float4 b4 = *(const float4*)&Bs[k2][tcol];
      double bx = (double)b4.x, by = (double)b4.y, bz = (double)b4.z, bw = (double)b4.w;
      acc[0][0] += a0 * bx; acc[0][1] += a0 * by; acc[0][2] += a0 * bz; acc[0][3] += a0 * bw;
      acc[1][0] += a1 * bx; acc[1][1] += a1 * by; acc[1][2] += a1 * bz; acc[1][3] += a1 * bw;
      acc[2][0] += a2 * bx; acc[2][1] += a2 * by; acc[2][2] += a2 * bz; acc[2][3] += a2 * bw;
      acc[3][0] += a3 * bx; acc[3][1] += a3 * by; acc[3][2] += a3 * bz; acc[3][3] += a3 * bw;
    }
  }
  const int ct = c0 + tcol;
  #pragma unroll
  for (int i = 0; i < 4; i++) {
    int row = r0 + trow + i;
    int b = row >> 7, s = row & 127;
    float v0 = (float)acc[i][0], v1 = (float)acc[i][1];
    float v2 = (float)acc[i][2], v3 = (float)acc[i][3];
    if (ct < 128) {
      int h = ct >> 4, j4 = (ct >> 2) & 3;
      float4 v = make_float4(v0, v1, v2, v3);
      ((float4*)gK4)[(((size_t)b * 8 + h) * 4 + j4) * 128 + s] = v;
    } else if (ct < 256) {
      float4 v = make_float4(v0, v1, v2, v3);
      *(float4*)&gVrow[((size_t)b * 128 + s) * 128 + (ct - 128)] = v;
    } else {
      int k = ct - 256;
      lKT[((size_t)b * 128 + k + 0) * 128 + s] = v0;
      lKT[((size_t)b * 128 + k + 1) * 128 + s] = v1;
      lKT[((size_t)b * 128 + k + 2) * 128 + s] = v2;
      lKT[((size_t)b * 128 + k + 3) * 128 + s] = v3;
    }
  }
}

// ---------------- decoder: 2 batch elements per 512-thread block ----------------
// Numeric contract (PROVEN r4/r5): f64 inner dots, f32 stage-round at every
// reference tensor boundary, exact-f32 state machine, f32 log_softmax
// quantization emulation. Structure: 9 barriers/step, replicated per-lane
// state machine (no thread0 serial phases), reg arrays for gV/W_out.
template<bool USE_ENCU>
__global__ __launch_bounds__(512, 2) void decoder_kernel(
    const float* __restrict__ loc, const float* __restrict__ scores,
    const float* __restrict__ Tmax, const int* __restrict__ m_in,
    const float* __restrict__ Wout, const float* __restrict__ Wupd,
    const float* __restrict__ enc,
    const float* __restrict__ gK4g, const float* __restrict__ gVrow,
    const float* __restrict__ lKTg, const float* __restrict__ encU,
    const float* __restrict__ hhat,
    const float* __restrict__ wtp, const float* __restrict__ wmp,
    const float* __restrict__ plcq, float* __restrict__ out)
{
  const int tid = threadIdx.x;
  const int sub = tid >> 8;            // which half (batch element)
  const int t256 = tid & 255;
  const int ln = tid & 63;
  const int b = blockIdx.x * 2 + sub;

  __shared__ float gK4L[2][16384];     // [h][j4][s] float4 layout (64 KB/half)
  __shared__ float comp[2][NH][129];   // compat -> attn (pad 129: P4 conflict-free)
  __shared__ double qd[2][DD];         // (double)fl32(query)
  __shared__ double bufA[2][SS][2];    // heads pairs, then logits pairs
  __shared__ double bufB[2][DD];       // headsd, then gld
  __shared__ double bufC[2][DD][2];    // glimpse pairs
  __shared__ float lx[2][SS], ly_[2][SS], dep[2][SS], sc_[2][SS];
  __shared__ int maskv[2][SS];
  __shared__ float lqtab[NSTEP];
  __shared__ float encrow[2][DD];

  // ---- stage gK4 into LDS (linear copy, coalesced) ----
  const float* gksrc = gK4g + (size_t)b * 16384;
  float* gkL = gK4L[sub];
  #pragma unroll
  for (int it = 0; it < 16; ++it) {
    int idx = t256 + 256 * it;         // float4 index 0..4095
    *(float4*)&gkL[idx * 4] = *(const float4*)&gksrc[idx * 4];
  }
  // ---- gV column -> registers (64 f32) ----
  float gvreg[64];
  {
    int c = t256 & 127, sb = (t256 >> 7) * 64;
    #pragma unroll
    for (int j = 0; j < 64; ++j)
      gvreg[j] = gVrow[((size_t)b * SS + sb + j) * DD + c];
  }
  // ---- W_out column-half -> registers (64 f32) ----
  float woreg[64];
  {
    int d = t256 & 127, kb = (t256 >> 7) * 64;
    #pragma unroll
    for (int j = 0; j < 64; ++j)
      woreg[j] = Wout[(size_t)(kb + j) * DD + d];
  }

  // ---- replicated state registers (identical across all threads of a half) ----
  float r_Tm = Tmax[b], r_T0 = r_Tm;
  int r_mm = m_in[b];
  int r_start = 1, r_last = 0, city_prev = 0;
  float r_total = 0.f;
  double r_logp = 0.0;

  if (t256 < SS) {
    lx[sub][t256]  = loc[((size_t)b * SS + t256) * 2];
    ly_[sub][t256] = loc[((size_t)b * SS + t256) * 2 + 1];
    sc_[sub][t256] = scores[(size_t)b * SS + t256];
    maskv[sub][t256] = (t256 < 2) ? 1 : 0;
  }
  if (tid < NSTEP) lqtab[tid] = (float)log((double)(NSTEP - tid));
  __syncthreads();
  if (t256 < SS) {
    float dx = __fsub_rn(lx[sub][t256], lx[sub][0]);
    float dy = __fsub_rn(ly_[sub][t256], ly_[sub][0]);
    dep[sub][t256] = __fsqrt_rn(__fadd_rn(__fadd_rn(__fmul_rn(dx, dx), __fmul_rn(dy, dy)), 1e-12f));
  }
  float hh_r = 0.f, wtp_r = 0.f, wmp_r = 0.f, plcq_r = 0.f, encu_pref = 0.f;
  if (t256 < DD) {
    hh_r = hhat[(size_t)b * DD + t256];
    wtp_r = wtp[t256]; wmp_r = wmp[t256]; plcq_r = plcq[t256];
  }

  for (int t = 0; t < NSTEP; ++t) {
    __syncthreads();                                   // B1 (state/mask boundary)
    // ---- P1: commit mask, compute query ----
    if (t256 == 0 && t > 0) maskv[sub][city_prev] = 1;
    if (!USE_ENCU) {
      if (t > 0 && t256 < DD)
        encrow[sub][t256] = enc[((size_t)b * SS + r_last) * DD + t256];
      __syncthreads();
    }
    if (t256 < DD) {
      double acc = (double)hh_r + (double)r_Tm * (double)wtp_r + (double)r_mm * (double)wmp_r;
      if (t == 0) {
        acc += (double)plcq_r;
      } else if (USE_ENCU) {
        acc += (double)encu_pref;
      } else {
        double s0 = 0.0;
        for (int k = 0; k < DD; k++) s0 += (double)encrow[sub][k] * (double)Wupd[(size_t)k * DD + t256];
        acc += s0;
      }
      qd[sub][t256] = (double)(float)acc;
    }
    __syncthreads();                                   // B2
    // ---- P2: compat = fl32(q . gK)*0.25, masked (b128 LDS reads) ----
    {
      int h = t256 >> 5, s0b = t256 & 31;
      double qq[16];
      #pragma unroll
      for (int j = 0; j < 16; ++j) qq[j] = qd[sub][h * 16 + j];
      #pragma unroll
      for (int i = 0; i < 4; ++i) {
        int s = s0b + 32 * i;
        double c = 0.0;
        #pragma unroll
        for (int j4 = 0; j4 < 4; ++j4) {
          float4 kv = *(float4*)&gkL[(((h * 4 + j4) * 128) + s) * 4];
          c += (double)kv.x * qq[j4 * 4 + 0] + (double)kv.y * qq[j4 * 4 + 1]
             + (double)kv.z * qq[j4 * 4 + 2] + (double)kv.w * qq[j4 * 4 + 3];
        }
        comp[sub][h][s] = maskv[sub][s] ? -INFINITY : __fmul_rn((float)c, 0.25f);
      }
    }
    __syncthreads();                                   // B3
    // ---- P3: softmax per head (wave handles 2 heads) ----
    {
      int w2 = (t256 >> 6);
      #pragma unroll
      for (int hh2 = 0; hh2 < 2; ++hh2) {
        int h = w2 * 2 + hh2;
        float a0 = comp[sub][h][ln], a1 = comp[sub][h][ln + 64];
        float mx = fmaxf(a0, a1);
        #pragma unroll
        for (int off = 32; off > 0; off >>= 1) mx = fmaxf(mx, __shfl_xor(mx, off));
        float e0 = expf(__fsub_rn(a0, mx)), e1 = expf(__fsub_rn(a1, mx));
        double sm = (double)e0 + (double)e1;
        #pragma unroll
        for (int off = 32; off > 0; off >>= 1) sm += __shfl_xor(sm, off);
        float sumf = (float)sm;
        comp[sub][h][ln]      = __fdiv_rn(e0, sumf);
        comp[sub][h][ln + 64] = __fdiv_rn(e1, sumf);
      }
    }
    __syncthreads();                                   // B4
    // ---- P4: heads partials -> bufA pairs ----
    {
      int c = t256 & 127, p = t256 >> 7, h = c >> 4, sb = p * 64;
      double a0 = 0, a1 = 0, a2 = 0, a3 = 0;
      #pragma unroll
      for (int j = 0; j < 64; j += 4) {
        a0 += (double)comp[sub][h][sb + j]     * (double)gvreg[j];
        a1 += (double)comp[sub][h][sb + j + 1] * (double)gvreg[j + 1];
        a2 += (double)comp[sub][h][sb + j + 2] * (double)gvreg[j + 2];
        a3 += (double)comp[sub][h][sb + j + 3] * (double)gvreg[j + 3];
      }
      bufA[sub][c][p] = (a0 + a1) + (a2 + a3);
    }
    __syncthreads();                                   // B5
    if (t256 < DD) bufB[sub][t256] = (double)(float)(bufA[sub][t256][0] + bufA[sub][t256][1]);
    __syncthreads();                                   // B6
    // ---- P5: glimpse partials -> bufC ----
    {
      int d = t256 & 127, kb = (t256 >> 7) * 64;
      double a0 = 0, a1 = 0, a2 = 0, a3 = 0;
      #pragma unroll
      for (int j = 0; j < 64; j += 4) {
        a0 += bufB[sub][kb + j]     * (double)woreg[j];
        a1 += bufB[sub][kb + j + 1] * (double)woreg[j + 1];
        a2 += bufB[sub][kb + j + 2] * (double)woreg[j + 2];
        a3 += bufB[sub][kb + j + 3] * (double)woreg[j + 3];
      }
      bufC[sub][d][t256 >> 7] = (a0 + a1) + (a2 + a3);
    }
    __syncthreads();                                   // B7
    if (t256 < DD) bufB[sub][t256] = (double)(float)(bufC[sub][t256][0] + bufC[sub][t256][1]);
    __syncthreads();                                   // B8
    // ---- P6: logits partials (logKT from global/L2, coalesced; mask-skip) ----
    {
      int s = t256 & 127, p2 = t256 >> 7, kb = p2 * 64;
      double r = 0.0;
      if (!maskv[sub][s]) {
        const float* lk = lKTg + ((size_t)b * 128 + kb) * 128 + s;
        double a0 = 0, a1 = 0, a2 = 0, a3 = 0;
        #pragma unroll
        for (int j = 0; j < 64; j += 4) {
          a0 += (double)lk[(j)     * 128] * bufB[sub][kb + j];
          a1 += (double)lk[(j + 1) * 128] * bufB[sub][kb + j + 1];
          a2 += (double)lk[(j + 2) * 128] * bufB[sub][kb + j + 2];
          a3 += (double)lk[(j + 3) * 128] * bufB[sub][kb + j + 3];
        }
        r = (a0 + a1) + (a2 + a3);
      }
      bufA[sub][s][p2] = r;
    }
    __syncthreads();                                   // B9
    // ---- P7: mega-phase, replicated per wave (no LDS writes) ----
    {
      double dt0 = bufA[sub][ln][0] + bufA[sub][ln][1];
      double dt1 = bufA[sub][ln + 64][0] + bufA[sub][ln + 64][1];
      int m0 = maskv[sub][ln], m1 = maskv[sub][ln + 64];
      float f0 = (float)dt0, f1 = (float)dt1;
      float l0 = m0 ? -INFINITY : __fmul_rn(tanhf(__fdiv_rn(f0, 11.313708498984761f)), 10.0f);
      float l1 = m1 ? -INFINITY : __fmul_rn(tanhf(__fdiv_rn(f1, 11.313708498984761f)), 10.0f);
      float mx = fmaxf(l0, l1);
      #pragma unroll
      for (int off = 32; off > 0; off >>= 1) mx = fmaxf(mx, __shfl_xor(mx, off));
      float sh0 = __fsub_rn(l0, mx), sh1 = __fsub_rn(l1, mx);
      float Lq = lqtab[t];
      float y0 = __fsub_rn(sh0, Lq), y1 = __fsub_rn(sh1, Lq);
      float yv = y0; int yi = ln;
      if (y1 > yv) { yv = y1; yi = ln + 64; }
      double e = (double)expf(sh0) + (double)expf(sh1);
      #pragma unroll
      for (int off = 32; off > 0; off >>= 1) {
        float ov = __shfl_xor(yv, off); int oi = __shfl_xor(yi, off);
        double oe = __shfl_xor(e, off);
        if (ov > yv || (ov == yv && oi < yi)) { yv = ov; yi = oi; }
        e += oe;
      }
      int city = yi;
      float a0s = __shfl(sh0, city & 63), a1s = __shfl(sh1, city & 63);
      float sh_c = (city < 64) ? a0s : a1s;
      r_logp += (double)sh_c - log(e);
      // state update 1 (exact f32, replicated)
      float dx = __fsub_rn(lx[sub][r_last], lx[sub][city]);
      float dy = __fsub_rn(ly_[sub][r_last], ly_[sub][city]);
      float d_lc = __fsqrt_rn(__fadd_rn(__fadd_rn(__fmul_rn(dx, dx), __fmul_rn(dy, dy)), 1e-12f));
      float d_cd = dep[sub][city];
      if (r_start) d_lc = d_cd;
      int isv = (__fadd_rn(d_lc, d_cd) <= r_Tm) ? 1 : 0;
      if (isv) { r_Tm = __fsub_rn(r_Tm, d_lc); r_total = __fadd_rn(r_total, sc_[sub][city]); }
      int startA = (isv && r_start) ? 0 : r_start;
      // all-greater (old last, old mask, new Tm); lane covers s=ln and s=ln+64
      int g0 = 1;
      if (ln >= 1) {
        float ax = __fsub_rn(lx[sub][r_last], lx[sub][ln]);
        float ay = __fsub_rn(ly_[sub][r_last], ly_[sub][ln]);
        float dlo = __fsqrt_rn(__fadd_rn(__fadd_rn(__fmul_rn(ax, ax), __fmul_rn(ay, ay)), 1e-12f));
        g0 = ((__fadd_rn(dlo, dep[sub][ln]) > r_Tm) || m0) ? 1 : 0;
      }
      int g1;
      {
        float ax = __fsub_rn(lx[sub][r_last], lx[sub][ln + 64]);
        float ay = __fsub_rn(ly_[sub][r_last], ly_[sub][ln + 64]);
        float dlo = __fsqrt_rn(__fadd_rn(__fadd_rn(__fmul_rn(ax, ax), __fmul_rn(ay, ay)), 1e-12f));
        g1 = ((__fadd_rn(dlo, dep[sub][ln + 64]) > r_Tm) || m1) ? 1 : 0;
      }
      int all_g = __all(g0 && g1) ? 1 : 0;
      int dbl = (all_g && (r_mm - 1 > 0)) ? 1 : 0;
      if (dbl) { r_mm -= 1; r_Tm = r_T0; }
      r_start = (startA || dbl) ? 1 : 0;
      if (isv) r_last = city;
      city_prev = city;
      if (t256 == 0) out[1024 + (size_t)b * NSTEP + t] = (float)city;
      // prefetch next encU row (latency hidden across B1)
      if (USE_ENCU && t + 1 < NSTEP && t256 < DD)
        encu_pref = encU[((size_t)b * SS + r_last) * DD + t256];
    }
  }
  if (t256 == 0) {
    out[b] = (float)r_logp;
    out[512 + b] = r_total;
  }
}

extern "C" void kernel_launch(void* const* d_in, const int* in_sizes, int n_in,
                              void* d_out, int out_size, void* d_ws, size_t ws_size,
                              hipStream_t stream) {
  const float* enc    = (const float*)d_in[0];
  const float* loc    = (const float*)d_in[1];
  const float* scores = (const float*)d_in[2];
  const float* Tmax   = (const float*)d_in[3];
  const int*   m_in   = (const int*)d_in[4];
  const float* W_ctx  = (const float*)d_in[5];
  const float* W_upd  = (const float*)d_in[6];
  const float* W_nodes= (const float*)d_in[7];
  const float* W_out  = (const float*)d_in[8];
  const float* vtmax  = (const float*)d_in[9];
  const float* vm     = (const float*)d_in[10];
  const float* Wplc   = (const float*)d_in[11];
  float* out = (float*)d_out;
  float* ws  = (float*)d_ws;

  float* gK4   = ws;                       // 8388608 floats (33.6 MB)
  float* gVrow = gK4 + 8388608;            // 8388608
  float* lKT   = gVrow + 8388608;          // 8388608
  float* hhat  = lKT + 8388608;            // 65536
  float* wtp   = hhat + 65536;             // 128
  float* wmp   = wtp + 128;                // 128
  float* plcq  = wmp + 128;                // 128
  float* encU  = plcq + 128;               // 8388608 (33.6 MB), optional

  const size_t need_base = ((size_t)3 * 8388608 + 65536 + 384) * 4;
  const size_t need_full = need_base + (size_t)8388608 * 4;
  const bool use_encu = ws_size >= need_full;

  proj_kernel<<<dim3(1), dim3(128), 0, stream>>>(vtmax, vm, Wplc, W_upd, wtp, wmp, plcq);
  hhat_kernel<<<dim3(NB), dim3(128), 0, stream>>>(enc, W_ctx, hhat);
  gemm_kvl<<<dim3(1024, 6), dim3(256), 0, stream>>>(enc, W_nodes, gK4, gVrow, lKT);
  if (use_encu) {
    gemm64<<<dim3(1024, 2), dim3(256), 0, stream>>>(enc, W_upd, 128, encU, 128);
    decoder_kernel<true><<<dim3(256), dim3(512), 0, stream>>>(loc, scores, Tmax, m_in, W_out, W_upd, enc,
                                                              gK4, gVrow, lKT, encU, hhat, wtp, wmp, plcq, out);
  } else {
    decoder_kernel<false><<<dim3(256), dim3(512), 0, stream>>>(loc, scores, Tmax, m_in, W_out, W_upd, enc,
                                                               gK4, gVrow, lKT, (const float*)nullptr, hhat, wtp, wmp, plcq, out);
  }
}

// Round 8
// 7098.889 us; speedup vs baseline: 1.0006x; 1.0006x over previous
//
#include <hip/hip_runtime.h>
#include <math.h>

#define NB 512
#define SS 128
#define DD 128
#define NH 8
#define NSTEP 126

// ---------------- precompute: wtp/wmp/plcq projections (f64 inner, f32 out) ----
__global__ __launch_bounds__(128) void proj_kernel(
    const float* __restrict__ vtmax, const float* __restrict__ vm,
    const float* __restrict__ wplc, const float* __restrict__ Wupd,
    float* __restrict__ wtp, float* __restrict__ wmp, float* __restrict__ plcq)
{
  int d = threadIdx.x;
  double a = 0.0, b = 0.0, c = 0.0;
  for (int k = 0; k < DD; k++) {
    a += (double)vtmax[k] * (double)Wupd[(size_t)(DD + k) * DD + d];
    b += (double)vm[k]    * (double)Wupd[(size_t)(2 * DD + k) * DD + d];
    c += (double)wplc[k]  * (double)Wupd[(size_t)k * DD + d];
  }
  wtp[d] = (float)a; wmp[d] = (float)b; plcq[d] = (float)c;
}

// ---------------- precompute: h_hat = mean(enc,1) @ W_ctx (f64 inner, f32 out) ----
__global__ __launch_bounds__(128) void hhat_kernel(
    const float* __restrict__ enc, const float* __restrict__ Wctx,
    float* __restrict__ hh)
{
  __shared__ double mean[DD];
  int b = blockIdx.x, d = threadIdx.x;
  double s = 0.0;
  for (int j = 0; j < SS; j++) s += (double)enc[((size_t)b * SS + j) * DD + d];
  mean[d] = s * (1.0 / 128.0);
  __syncthreads();
  double a = 0.0;
  for (int k = 0; k < DD; k++) a += mean[k] * (double)Wctx[(size_t)k * DD + d];
  hh[(size_t)b * DD + d] = (float)a;
}

// ---- generic GEMM (f64 accumulate, f32 out): C = A(65536x128) @ B(128 x ncols) ----
__global__ __launch_bounds__(256) void gemm64(
    const float* __restrict__ A, const float* __restrict__ Bm, int ldb,
    float* __restrict__ C, int ldc)
{
  __shared__ float As[64][132];
  __shared__ float Bs[64][68];
  const int r0 = blockIdx.x * 64;
  const int c0 = blockIdx.y * 64;
  const int tid = threadIdx.x;
  #pragma unroll
  for (int i = 0; i < 8; i++) {
    int idx = tid + 256 * i;
    int rr = idx >> 5;
    int cc = (idx & 31) << 2;
    *(float4*)&As[rr][cc] = *(const float4*)&A[(size_t)(r0 + rr) * DD + cc];
  }
  const int trow = (tid >> 4) << 2;
  const int tcol = (tid & 15) << 2;
  double acc[4][4] = {};
  for (int kh = 0; kh < 2; kh++) {
    __syncthreads();
    #pragma unroll
    for (int i = 0; i < 4; i++) {
      int idx = tid + 256 * i;
      int rr = idx >> 4;
      int cc = (idx & 15) << 2;
      *(float4*)&Bs[rr][cc] = *(const float4*)&Bm[(size_t)(kh * 64 + rr) * ldb + c0 + cc];
    }
    __syncthreads();
    #pragma unroll 2
    for (int k2 = 0; k2 < 64; k2++) {
      int k = kh * 64 + k2;
      double a0 = (double)As[trow][k],     a1 = (double)As[trow + 1][k],
             a2 = (double)As[trow + 2][k], a3 = (double)As[trow + 3][k];
      float4 b4 = *(const float4*)&Bs[k2][tcol];
      double bx = (double)b4.x, by = (double)b4.y, bz = (double)b4.z, bw = (double)b4.w;
      acc[0][0] += a0 * bx; acc[0][1] += a0 * by; acc[0][2] += a0 * bz; acc[0][3] += a0 * bw;
      acc[1][0] += a1 * bx; acc[1][1] += a1 * by; acc[1][2] += a1 * bz; acc[1][3] += a1 * bw;
      acc[2][0] += a2 * bx; acc[2][1] += a2 * by; acc[2][2] += a2 * bz; acc[2][3] += a2 * bw;
      acc[3][0] += a3 * bx; acc[3][1] += a3 * by; acc[3][2] += a3 * bz; acc[3][3] += a3 * bw;
    }
  }
  #pragma unroll
  for (int i = 0; i < 4; i++) {
    float* cp = &C[(size_t)(r0 + trow + i) * ldc + c0 + tcol];
    cp[0] = (float)acc[i][0]; cp[1] = (float)acc[i][1];
    cp[2] = (float)acc[i][2]; cp[3] = (float)acc[i][3];
  }
}

// ---- kvl GEMM with layout-split epilogue: gK4 [b][h][j4][s]x4, gVrow [b][s][c], logKT [b][k][s]
__global__ __launch_bounds__(256) void gemm_kvl(
    const float* __restrict__ A, const float* __restrict__ Bm,
    float* __restrict__ gK4, float* __restrict__ gVrow, float* __restrict__ lKT)
{
  __shared__ float As[64][132];
  __shared__ float Bs[64][68];
  const int r0 = blockIdx.x * 64;
  const int c0 = blockIdx.y * 64;
  const int tid = threadIdx.x;
  #pragma unroll
  for (int i = 0; i < 8; i++) {
    int idx = tid + 256 * i;
    int rr = idx >> 5;
    int cc = (idx & 31) << 2;
    *(float4*)&As[rr][cc] = *(const float4*)&A[(size_t)(r0 + rr) * DD + cc];
  }
  const int trow = (tid >> 4) << 2;
  const int tcol = (tid & 15) << 2;
  double acc[4][4] = {};
  for (int kh = 0; kh < 2; kh++) {
    __syncthreads();
    #pragma unroll
    for (int i = 0; i < 4; i++) {
      int idx = tid + 256 * i;
      int rr = idx >> 4;
      int cc = (idx & 15) << 2;
      *(float4*)&Bs[rr][cc] = *(const float4*)&Bm[(size_t)(kh * 64 + rr) * 384 + c0 + cc];
    }
    __syncthreads();
    #pragma unroll 2
    for (int k2 = 0; k2 < 64; k2++) {
      int k = kh * 64 + k2;
      double a0 = (double)As[trow][k],     a1 = (double)As[trow + 1][k],
             a2 = (double)As[trow + 2][k], a3 = (double)As[trow + 3][k];
      float4 b4 = *(const float4*)&Bs[k2][tcol];
      double bx = (double)b4.x, by = (double)b4.y, bz = (double)b4.z, bw = (double)b4.w;
      acc[0][0] += a0 * bx; acc[0][1] += a0 * by; acc[0][2] += a0 * bz; acc[0][3] += a0 * bw;
      acc[1][0] += a1 * bx; acc[1][1] += a1 * by; acc[1][2] += a1 * bz; acc[1][3] += a1 * bw;
      acc[2][0] += a2 * bx; acc[2][1] += a2 * by; acc[2][2] += a2 * bz; acc[2][3] += a2 * bw;
      acc[3][0] += a3 * bx; acc[3][1] += a3 * by; acc[3][2] += a3 * bz; acc[3][3] += a3 * bw;
    }
  }
  const int ct = c0 + tcol;
  #pragma unroll
  for (int i = 0; i < 4; i++) {
    int row = r0 + trow + i;
    int b = row >> 7, s = row & 127;
    float v0 = (float)acc[i][0], v1 = (float)acc[i][1];
    float v2 = (float)acc[i][2], v3 = (float)acc[i][3];
    if (ct < 128) {
      int h = ct >> 4, j4 = (ct >> 2) & 3;
      float4 v = make_float4(v0, v1, v2, v3);
      ((float4*)gK4)[(((size_t)b * 8 + h) * 4 + j4) * 128 + s] = v;
    } else if (ct < 256) {
      float4 v = make_float4(v0, v1, v2, v3);
      *(float4*)&gVrow[((size_t)b * 128 + s) * 128 + (ct - 128)] = v;
    } else {
      int k = ct - 256;
      lKT[((size_t)b * 128 + k + 0) * 128 + s] = v0;
      lKT[((size_t)b * 128 + k + 1) * 128 + s] = v1;
      lKT[((size_t)b * 128 + k + 2) * 128 + s] = v2;
      lKT[((size_t)b * 128 + k + 3) * 128 + s] = v3;
    }
  }
}

// ---------------- decoder: 2 batch elements per 512-thread block ----------------
// Numeric contract (PROVEN r4/r5): f64 inner dots, f32 stage-round at every
// reference tensor boundary, exact-f32 state machine, f32 log_softmax
// quantization emulation. Structure: replicated per-lane state machine (no
// thread0 serial phases), reg arrays for gV/W_out.
// __launch_bounds__(512, 1): second arg MUST be 1 — empirically N=2 caps
// VGPR at 128 and spills the 128-reg arrays (r6: 116MB, r7: 121MB scratch).
template<bool USE_ENCU>
__global__ __launch_bounds__(512, 1) void decoder_kernel(
    const float* __restrict__ loc, const float* __restrict__ scores,
    const float* __restrict__ Tmax, const int* __restrict__ m_in,
    const float* __restrict__ Wout, const float* __restrict__ Wupd,
    const float* __restrict__ enc,
    const float* __restrict__ gK4g, const float* __restrict__ gVrow,
    const float* __restrict__ lKTg, const float* __restrict__ encU,
    const float* __restrict__ hhat,
    const float* __restrict__ wtp, const float* __restrict__ wmp,
    const float* __restrict__ plcq, float* __restrict__ out)
{
  const int tid = threadIdx.x;
  const int sub = tid >> 8;            // which half (batch element)
  const int t256 = tid & 255;
  const int ln = tid & 63;
  const int b = blockIdx.x * 2 + sub;

  __shared__ float gK4L[2][16384];     // [h][j4][s] float4 layout (64 KB/half)
  __shared__ float comp[2][NH][129];   // compat -> attn (pad 129: P4 conflict-free)
  __shared__ double qd[2][DD];         // (double)fl32(query)
  __shared__ double bufA[2][SS][2];    // heads pairs, then logits pairs
  __shared__ double bufB[2][DD];       // headsd, then gld
  __shared__ double bufC[2][DD][2];    // glimpse pairs
  __shared__ float lx[2][SS], ly_[2][SS], dep[2][SS], sc_[2][SS];
  __shared__ int maskv[2][SS];
  __shared__ float lqtab[NSTEP];
  __shared__ float encrow[2][DD];

  // ---- stage gK4 into LDS (linear copy, coalesced) ----
  const float* gksrc = gK4g + (size_t)b * 16384;
  float* gkL = gK4L[sub];
  #pragma unroll
  for (int it = 0; it < 16; ++it) {
    int idx = t256 + 256 * it;         // float4 index 0..4095
    *(float4*)&gkL[idx * 4] = *(const float4*)&gksrc[idx * 4];
  }
  // ---- gV column -> registers (64 f32) ----
  float gvreg[64];
  {
    int c = t256 & 127, sb = (t256 >> 7) * 64;
    #pragma unroll
    for (int j = 0; j < 64; ++j)
      gvreg[j] = gVrow[((size_t)b * SS + sb + j) * DD + c];
  }
  // ---- W_out column-half -> registers (64 f32) ----
  float woreg[64];
  {
    int d = t256 & 127, kb = (t256 >> 7) * 64;
    #pragma unroll
    for (int j = 0; j < 64; ++j)
      woreg[j] = Wout[(size_t)(kb + j) * DD + d];
  }

  // ---- replicated state registers (identical across all threads of a half) ----
  float r_Tm = Tmax[b], r_T0 = r_Tm;
  int r_mm = m_in[b];
  int r_start = 1, r_last = 0, city_prev = 0;
  float r_total = 0.f;
  double r_logp = 0.0;

  if (t256 < SS) {
    lx[sub][t256]  = loc[((size_t)b * SS + t256) * 2];
    ly_[sub][t256] = loc[((size_t)b * SS + t256) * 2 + 1];
    sc_[sub][t256] = scores[(size_t)b * SS + t256];
    maskv[sub][t256] = (t256 < 2) ? 1 : 0;
  }
  if (tid < NSTEP) lqtab[tid] = (float)log((double)(NSTEP - tid));
  __syncthreads();
  if (t256 < SS) {
    float dx = __fsub_rn(lx[sub][t256], lx[sub][0]);
    float dy = __fsub_rn(ly_[sub][t256], ly_[sub][0]);
    dep[sub][t256] = __fsqrt_rn(__fadd_rn(__fadd_rn(__fmul_rn(dx, dx), __fmul_rn(dy, dy)), 1e-12f));
  }
  float hh_r = 0.f, wtp_r = 0.f, wmp_r = 0.f, plcq_r = 0.f, encu_pref = 0.f;
  if (t256 < DD) {
    hh_r = hhat[(size_t)b * DD + t256];
    wtp_r = wtp[t256]; wmp_r = wmp[t256]; plcq_r = plcq[t256];
  }

  for (int t = 0; t < NSTEP; ++t) {
    __syncthreads();                                   // B1 (state/mask boundary)
    // ---- P1: commit mask, compute query ----
    if (t256 == 0 && t > 0) maskv[sub][city_prev] = 1;
    if (!USE_ENCU) {
      if (t > 0 && t256 < DD)
        encrow[sub][t256] = enc[((size_t)b * SS + r_last) * DD + t256];
      __syncthreads();
    }
    if (t256 < DD) {
      double acc = (double)hh_r + (double)r_Tm * (double)wtp_r + (double)r_mm * (double)wmp_r;
      if (t == 0) {
        acc += (double)plcq_r;
      } else if (USE_ENCU) {
        acc += (double)encu_pref;
      } else {
        double s0 = 0.0;
        for (int k = 0; k < DD; k++) s0 += (double)encrow[sub][k] * (double)Wupd[(size_t)k * DD + t256];
        acc += s0;
      }
      qd[sub][t256] = (double)(float)acc;
    }
    __syncthreads();                                   // B2
    // ---- P2: compat = fl32(q . gK)*0.25, masked (b128 LDS reads) ----
    {
      int h = t256 >> 5, s0b = t256 & 31;
      double qq[16];
      #pragma unroll
      for (int j = 0; j < 16; ++j) qq[j] = qd[sub][h * 16 + j];
      #pragma unroll
      for (int i = 0; i < 4; ++i) {
        int s = s0b + 32 * i;
        double c = 0.0;
        #pragma unroll
        for (int j4 = 0; j4 < 4; ++j4) {
          float4 kv = *(float4*)&gkL[(((h * 4 + j4) * 128) + s) * 4];
          c += (double)kv.x * qq[j4 * 4 + 0] + (double)kv.y * qq[j4 * 4 + 1]
             + (double)kv.z * qq[j4 * 4 + 2] + (double)kv.w * qq[j4 * 4 + 3];
        }
        comp[sub][h][s] = maskv[sub][s] ? -INFINITY : __fmul_rn((float)c, 0.25f);
      }
    }
    __syncthreads();                                   // B3
    // ---- P3: softmax per head (wave handles 2 heads) ----
    {
      int w2 = (t256 >> 6);
      #pragma unroll
      for (int hh2 = 0; hh2 < 2; ++hh2) {
        int h = w2 * 2 + hh2;
        float a0 = comp[sub][h][ln], a1 = comp[sub][h][ln + 64];
        float mx = fmaxf(a0, a1);
        #pragma unroll
        for (int off = 32; off > 0; off >>= 1) mx = fmaxf(mx, __shfl_xor(mx, off));
        float e0 = expf(__fsub_rn(a0, mx)), e1 = expf(__fsub_rn(a1, mx));
        double sm = (double)e0 + (double)e1;
        #pragma unroll
        for (int off = 32; off > 0; off >>= 1) sm += __shfl_xor(sm, off);
        float sumf = (float)sm;
        comp[sub][h][ln]      = __fdiv_rn(e0, sumf);
        comp[sub][h][ln + 64] = __fdiv_rn(e1, sumf);
      }
    }
    __syncthreads();                                   // B4
    // ---- P4: heads partials -> bufA pairs ----
    {
      int c = t256 & 127, p = t256 >> 7, h = c >> 4, sb = p * 64;
      double a0 = 0, a1 = 0, a2 = 0, a3 = 0;
      #pragma unroll
      for (int j = 0; j < 64; j += 4) {
        a0 += (double)comp[sub][h][sb + j]     * (double)gvreg[j];
        a1 += (double)comp[sub][h][sb + j + 1] * (double)gvreg[j + 1];
        a2 += (double)comp[sub][h][sb + j + 2] * (double)gvreg[j + 2];
        a3 += (double)comp[sub][h][sb + j + 3] * (double)gvreg[j + 3];
      }
      bufA[sub][c][p] = (a0 + a1) + (a2 + a3);
    }
    __syncthreads();                                   // B5
    if (t256 < DD) bufB[sub][t256] = (double)(float)(bufA[sub][t256][0] + bufA[sub][t256][1]);
    __syncthreads();                                   // B6
    // ---- P5: glimpse partials -> bufC ----
    {
      int d = t256 & 127, kb = (t256 >> 7) * 64;
      double a0 = 0, a1 = 0, a2 = 0, a3 = 0;
      #pragma unroll
      for (int j = 0; j < 64; j += 4) {
        a0 += bufB[sub][kb + j]     * (double)woreg[j];
        a1 += bufB[sub][kb + j + 1] * (double)woreg[j + 1];
        a2 += bufB[sub][kb + j + 2] * (double)woreg[j + 2];
        a3 += bufB[sub][kb + j + 3] * (double)woreg[j + 3];
      }
      bufC[sub][d][t256 >> 7] = (a0 + a1) + (a2 + a3);
    }
    __syncthreads();                                   // B7
    if (t256 < DD) bufB[sub][t256] = (double)(float)(bufC[sub][t256][0] + bufC[sub][t256][1]);
    __syncthreads();                                   // B8
    // ---- P6: logits partials (logKT from global/L2, coalesced; mask-skip) ----
    {
      int s = t256 & 127, p2 = t256 >> 7, kb = p2 * 64;
      double r = 0.0;
      if (!maskv[sub][s]) {
        const float* lk = lKTg + ((size_t)b * 128 + kb) * 128 + s;
        double a0 = 0, a1 = 0, a2 = 0, a3 = 0;
        #pragma unroll
        for (int j = 0; j < 64; j += 4) {
          a0 += (double)lk[(j)     * 128] * bufB[sub][kb + j];
          a1 += (double)lk[(j + 1) * 128] * bufB[sub][kb + j + 1];
          a2 += (double)lk[(j + 2) * 128] * bufB[sub][kb + j + 2];
          a3 += (double)lk[(j + 3) * 128] * bufB[sub][kb + j + 3];
        }
        r = (a0 + a1) + (a2 + a3);
      }
      bufA[sub][s][p2] = r;
    }
    __syncthreads();                                   // B9
    // ---- P7: mega-phase, replicated per wave (no LDS writes) ----
    {
      double dt0 = bufA[sub][ln][0] + bufA[sub][ln][1];
      double dt1 = bufA[sub][ln + 64][0] + bufA[sub][ln + 64][1];
      int m0 = maskv[sub][ln], m1 = maskv[sub][ln + 64];
      float f0 = (float)dt0, f1 = (float)dt1;
      float l0 = m0 ? -INFINITY : __fmul_rn(tanhf(__fdiv_rn(f0, 11.313708498984761f)), 10.0f);
      float l1 = m1 ? -INFINITY : __fmul_rn(tanhf(__fdiv_rn(f1, 11.313708498984761f)), 10.0f);
      float mx = fmaxf(l0, l1);
      #pragma unroll
      for (int off = 32; off > 0; off >>= 1) mx = fmaxf(mx, __shfl_xor(mx, off));
      float sh0 = __fsub_rn(l0, mx), sh1 = __fsub_rn(l1, mx);
      float Lq = lqtab[t];
      float y0 = __fsub_rn(sh0, Lq), y1 = __fsub_rn(sh1, Lq);
      float yv = y0; int yi = ln;
      if (y1 > yv) { yv = y1; yi = ln + 64; }
      double e = (double)expf(sh0) + (double)expf(sh1);
      #pragma unroll
      for (int off = 32; off > 0; off >>= 1) {
        float ov = __shfl_xor(yv, off); int oi = __shfl_xor(yi, off);
        double oe = __shfl_xor(e, off);
        if (ov > yv || (ov == yv && oi < yi)) { yv = ov; yi = oi; }
        e += oe;
      }
      int city = yi;
      float a0s = __shfl(sh0, city & 63), a1s = __shfl(sh1, city & 63);
      float sh_c = (city < 64) ? a0s : a1s;
      r_logp += (double)sh_c - log(e);
      // state update 1 (exact f32, replicated)
      float dx = __fsub_rn(lx[sub][r_last], lx[sub][city]);
      float dy = __fsub_rn(ly_[sub][r_last], ly_[sub][city]);
      float d_lc = __fsqrt_rn(__fadd_rn(__fadd_rn(__fmul_rn(dx, dx), __fmul_rn(dy, dy)), 1e-12f));
      float d_cd = dep[sub][city];
      if (r_start) d_lc = d_cd;
      int isv = (__fadd_rn(d_lc, d_cd) <= r_Tm) ? 1 : 0;
      if (isv) { r_Tm = __fsub_rn(r_Tm, d_lc); r_total = __fadd_rn(r_total, sc_[sub][city]); }
      int startA = (isv && r_start) ? 0 : r_start;
      // all-greater (old last, old mask, new Tm); lane covers s=ln and s=ln+64
      int g0 = 1;
      if (ln >= 1) {
        float ax = __fsub_rn(lx[sub][r_last], lx[sub][ln]);
        float ay = __fsub_rn(ly_[sub][r_last], ly_[sub][ln]);
        float dlo = __fsqrt_rn(__fadd_rn(__fadd_rn(__fmul_rn(ax, ax), __fmul_rn(ay, ay)), 1e-12f));
        g0 = ((__fadd_rn(dlo, dep[sub][ln]) > r_Tm) || m0) ? 1 : 0;
      }
      int g1;
      {
        float ax = __fsub_rn(lx[sub][r_last], lx[sub][ln + 64]);
        float ay = __fsub_rn(ly_[sub][r_last], ly_[sub][ln + 64]);
        float dlo = __fsqrt_rn(__fadd_rn(__fadd_rn(__fmul_rn(ax, ax), __fmul_rn(ay, ay)), 1e-12f));
        g1 = ((__fadd_rn(dlo, dep[sub][ln + 64]) > r_Tm) || m1) ? 1 : 0;
      }
      int all_g = __all(g0 && g1) ? 1 : 0;
      int dbl = (all_g && (r_mm - 1 > 0)) ? 1 : 0;
      if (dbl) { r_mm -= 1; r_Tm = r_T0; }
      r_start = (startA || dbl) ? 1 : 0;
      if (isv) r_last = city;
      city_prev = city;
      if (t256 == 0) out[1024 + (size_t)b * NSTEP + t] = (float)city;
      // prefetch next encU row (latency hidden across B1)
      if (USE_ENCU && t + 1 < NSTEP && t256 < DD)
        encu_pref = encU[((size_t)b * SS + r_last) * DD + t256];
    }
  }
  if (t256 == 0) {
    out[b] = (float)r_logp;
    out[512 + b] = r_total;
  }
}

extern "C" void kernel_launch(void* const* d_in, const int* in_sizes, int n_in,
                              void* d_out, int out_size, void* d_ws, size_t ws_size,
                              hipStream_t stream) {
  const float* enc    = (const float*)d_in[0];
  const float* loc    = (const float*)d_in[1];
  const float* scores = (const float*)d_in[2];
  const float* Tmax   = (const float*)d_in[3];
  const int*   m_in   = (const int*)d_in[4];
  const float* W_ctx  = (const float*)d_in[5];
  const float* W_upd  = (const float*)d_in[6];
  const float* W_nodes= (const float*)d_in[7];
  const float* W_out  = (const float*)d_in[8];
  const float* vtmax  = (const float*)d_in[9];
  const float* vm     = (const float*)d_in[10];
  const float* Wplc   = (const float*)d_in[11];
  float* out = (float*)d_out;
  float* ws  = (float*)d_ws;

  float* gK4   = ws;                       // 8388608 floats (33.6 MB)
  float* gVrow = gK4 + 8388608;            // 8388608
  float* lKT   = gVrow + 8388608;          // 8388608
  float* hhat  = lKT + 8388608;            // 65536
  float* wtp   = hhat + 65536;             // 128
  float* wmp   = wtp + 128;                // 128
  float* plcq  = wmp + 128;                // 128
  float* encU  = plcq + 128;               // 8388608 (33.6 MB), optional

  const size_t need_base = ((size_t)3 * 8388608 + 65536 + 384) * 4;
  const size_t need_full = need_base + (size_t)8388608 * 4;
  const bool use_encu = ws_size >= need_full;

  proj_kernel<<<dim3(1), dim3(128), 0, stream>>>(vtmax, vm, Wplc, W_upd, wtp, wmp, plcq);
  hhat_kernel<<<dim3(NB), dim3(128), 0, stream>>>(enc, W_ctx, hhat);
  gemm_kvl<<<dim3(1024, 6), dim3(256), 0, stream>>>(enc, W_nodes, gK4, gVrow, lKT);
  if (use_encu) {
    gemm64<<<dim3(1024, 2), dim3(256), 0, stream>>>(enc, W_upd, 128, encU, 128);
    decoder_kernel<true><<<dim3(256), dim3(512), 0, stream>>>(loc, scores, Tmax, m_in, W_out, W_upd, enc,
                                                              gK4, gVrow, lKT, encU, hhat, wtp, wmp, plcq, out);
  } else {
    decoder_kernel<false><<<dim3(256), dim3(512), 0, stream>>>(loc, scores, Tmax, m_in, W_out, W_upd, enc,
                                                               gK4, gVrow, lKT, (const float*)nullptr, hhat, wtp, wmp, plcq, out);
  }
}

// Round 9
// 4130.571 us; speedup vs baseline: 1.7196x; 1.7186x over previous
//
#include <hip/hip_runtime.h>
#include <math.h>

#define NB 512
#define SS 128
#define DD 128
#define NH 8
#define NSTEP 126

// ---------------- precompute: wtp/wmp/plcq projections (f64 inner, f32 out) ----
__global__ __launch_bounds__(128) void proj_kernel(
    const float* __restrict__ vtmax, const float* __restrict__ vm,
    const float* __restrict__ wplc, const float* __restrict__ Wupd,
    float* __restrict__ wtp, float* __restrict__ wmp, float* __restrict__ plcq)
{
  int d = threadIdx.x;
  double a = 0.0, b = 0.0, c = 0.0;
  for (int k = 0; k < DD; k++) {
    a += (double)vtmax[k] * (double)Wupd[(size_t)(DD + k) * DD + d];
    b += (double)vm[k]    * (double)Wupd[(size_t)(2 * DD + k) * DD + d];
    c += (double)wplc[k]  * (double)Wupd[(size_t)k * DD + d];
  }
  wtp[d] = (float)a; wmp[d] = (float)b; plcq[d] = (float)c;
}

// ---------------- precompute: h_hat = mean(enc,1) @ W_ctx (f64 inner, f32 out) ----
__global__ __launch_bounds__(128) void hhat_kernel(
    const float* __restrict__ enc, const float* __restrict__ Wctx,
    float* __restrict__ hh)
{
  __shared__ double mean[DD];
  int b = blockIdx.x, d = threadIdx.x;
  double s = 0.0;
  for (int j = 0; j < SS; j++) s += (double)enc[((size_t)b * SS + j) * DD + d];
  mean[d] = s * (1.0 / 128.0);
  __syncthreads();
  double a = 0.0;
  for (int k = 0; k < DD; k++) a += mean[k] * (double)Wctx[(size_t)k * DD + d];
  hh[(size_t)b * DD + d] = (float)a;
}

// ---- generic GEMM (f64 accumulate, f32 out): C = A(65536x128) @ B(128 x ncols) ----
__global__ __launch_bounds__(256) void gemm64(
    const float* __restrict__ A, const float* __restrict__ Bm, int ldb,
    float* __restrict__ C, int ldc)
{
  __shared__ float As[64][132];
  __shared__ float Bs[64][68];
  const int r0 = blockIdx.x * 64;
  const int c0 = blockIdx.y * 64;
  const int tid = threadIdx.x;
  #pragma unroll
  for (int i = 0; i < 8; i++) {
    int idx = tid + 256 * i;
    int rr = idx >> 5;
    int cc = (idx & 31) << 2;
    *(float4*)&As[rr][cc] = *(const float4*)&A[(size_t)(r0 + rr) * DD + cc];
  }
  const int trow = (tid >> 4) << 2;
  const int tcol = (tid & 15) << 2;
  double acc[4][4] = {};
  for (int kh = 0; kh < 2; kh++) {
    __syncthreads();
    #pragma unroll
    for (int i = 0; i < 4; i++) {
      int idx = tid + 256 * i;
      int rr = idx >> 4;
      int cc = (idx & 15) << 2;
      *(float4*)&Bs[rr][cc] = *(const float4*)&Bm[(size_t)(kh * 64 + rr) * ldb + c0 + cc];
    }
    __syncthreads();
    #pragma unroll 2
    for (int k2 = 0; k2 < 64; k2++) {
      int k = kh * 64 + k2;
      double a0 = (double)As[trow][k],     a1 = (double)As[trow + 1][k],
             a2 = (double)As[trow + 2][k], a3 = (double)As[trow + 3][k];
      float4 b4 = *(const float4*)&Bs[k2][tcol];
      double bx = (double)b4.x, by = (double)b4.y, bz = (double)b4.z, bw = (double)b4.w;
      acc[0][0] += a0 * bx; acc[0][1] += a0 * by; acc[0][2] += a0 * bz; acc[0][3] += a0 * bw;
      acc[1][0] += a1 * bx; acc[1][1] += a1 * by; acc[1][2] += a1 * bz; acc[1][3] += a1 * bw;
      acc[2][0] += a2 * bx; acc[2][1] += a2 * by; acc[2][2] += a2 * bz; acc[2][3] += a2 * bw;
      acc[3][0] += a3 * bx; acc[3][1] += a3 * by; acc[3][2] += a3 * bz; acc[3][3] += a3 * bw;
    }
  }
  #pragma unroll
  for (int i = 0; i < 4; i++) {
    float* cp = &C[(size_t)(r0 + trow + i) * ldc + c0 + tcol];
    cp[0] = (float)acc[i][0]; cp[1] = (float)acc[i][1];
    cp[2] = (float)acc[i][2]; cp[3] = (float)acc[i][3];
  }
}

// ---- kvl GEMM with layout-split epilogue: gK4 [b][h][j4][s]x4, gVrow [b][s][c], logKT [b][k][s]
__global__ __launch_bounds__(256) void gemm_kvl(
    const float* __restrict__ A, const float* __restrict__ Bm,
    float* __restrict__ gK4, float* __restrict__ gVrow, float* __restrict__ lKT)
{
  __shared__ float As[64][132];
  __shared__ float Bs[64][68];
  const int r0 = blockIdx.x * 64;
  const int c0 = blockIdx.y * 64;
  const int tid = threadIdx.x;
  #pragma unroll
  for (int i = 0; i < 8; i++) {
    int idx = tid + 256 * i;
    int rr = idx >> 5;
    int cc = (idx & 31) << 2;
    *(float4*)&As[rr][cc] = *(const float4*)&A[(size_t)(r0 + rr) * DD + cc];
  }
  const int trow = (tid >> 4) << 2;
  const int tcol = (tid & 15) << 2;
  double acc[4][4] = {};
  for (int kh = 0; kh < 2; kh++) {
    __syncthreads();
    #pragma unroll
    for (int i = 0; i < 4; i++) {
      int idx = tid + 256 * i;
      int rr = idx >> 4;
      int cc = (idx & 15) << 2;
      *(float4*)&Bs[rr][cc] = *(const float4*)&Bm[(size_t)(kh * 64 + rr) * 384 + c0 + cc];
    }
    __syncthreads();
    #pragma unroll 2
    for (int k2 = 0; k2 < 64; k2++) {
      int k = kh * 64 + k2;
      double a0 = (double)As[trow][k],     a1 = (double)As[trow + 1][k],
             a2 = (double)As[trow + 2][k], a3 = (double)As[trow + 3][k];
      float4 b4 = *(const float4*)&Bs[k2][tcol];
      double bx = (double)b4.x, by = (double)b4.y, bz = (double)b4.z, bw = (double)b4.w;
      acc[0][0] += a0 * bx; acc[0][1] += a0 * by; acc[0][2] += a0 * bz; acc[0][3] += a0 * bw;
      acc[1][0] += a1 * bx; acc[1][1] += a1 * by; acc[1][2] += a1 * bz; acc[1][3] += a1 * bw;
      acc[2][0] += a2 * bx; acc[2][1] += a2 * by; acc[2][2] += a2 * bz; acc[2][3] += a2 * bw;
      acc[3][0] += a3 * bx; acc[3][1] += a3 * by; acc[3][2] += a3 * bz; acc[3][3] += a3 * bw;
    }
  }
  const int ct = c0 + tcol;
  #pragma unroll
  for (int i = 0; i < 4; i++) {
    int row = r0 + trow + i;
    int b = row >> 7, s = row & 127;
    float v0 = (float)acc[i][0], v1 = (float)acc[i][1];
    float v2 = (float)acc[i][2], v3 = (float)acc[i][3];
    if (ct < 128) {
      int h = ct >> 4, j4 = (ct >> 2) & 3;
      float4 v = make_float4(v0, v1, v2, v3);
      ((float4*)gK4)[(((size_t)b * 8 + h) * 4 + j4) * 128 + s] = v;
    } else if (ct < 256) {
      float4 v = make_float4(v0, v1, v2, v3);
      *(float4*)&gVrow[((size_t)b * 128 + s) * 128 + (ct - 128)] = v;
    } else {
      int k = ct - 256;
      lKT[((size_t)b * 128 + k + 0) * 128 + s] = v0;
      lKT[((size_t)b * 128 + k + 1) * 128 + s] = v1;
      lKT[((size_t)b * 128 + k + 2) * 128 + s] = v2;
      lKT[((size_t)b * 128 + k + 3) * 128 + s] = v3;
    }
  }
}

// ---------------- decoder: one batch element per 256-thread block ----------------
// Numeric contract (PROVEN r4/r5): f64 inner dots, f32 stage-round at every
// reference tensor boundary, exact-f32 state machine, f32 log_softmax
// quantization emulation.
// Resource design (r5-r8 lessons): 256-thread block + __launch_bounds__(256,1)
// is the ONLY config where the 128-reg gv/wo arrays stay in registers (r5: 184
// VGPR, no spill; (256,2)/(512,*) cap VGPR at 128 -> 120MB scratch). LDS kept
// <=78KB so 2 blocks/CU co-reside NATURALLY (runtime packs by actual usage):
// 8 waves/CU, whole grid in one round, cross-block stall interleaving.
template<bool USE_ENCU>
__global__ __launch_bounds__(256, 1) void decoder_kernel(
    const float* __restrict__ loc, const float* __restrict__ scores,
    const float* __restrict__ Tmax, const int* __restrict__ m_in,
    const float* __restrict__ Wout, const float* __restrict__ Wupd,
    const float* __restrict__ enc,
    const float* __restrict__ gK4g, const float* __restrict__ gVrow,
    const float* __restrict__ lKTg, const float* __restrict__ encU,
    const float* __restrict__ hhat,
    const float* __restrict__ wtp, const float* __restrict__ wmp,
    const float* __restrict__ plcq, float* __restrict__ out)
{
  const int tid = threadIdx.x;
  const int ln = tid & 63;
  const int b = blockIdx.x;

  __shared__ float gK4L[16384];        // [h][j4][s] float4 layout (64 KB)
  __shared__ float comp[NH][129];      // compat -> attn (pad 129)
  __shared__ double qd[DD];            // (double)fl32(query)
  __shared__ double bufA[SS][2];       // heads pairs, then logits pairs
  __shared__ double bufB[DD];          // headsd, then gld
  __shared__ double bufC[DD][2];       // glimpse pairs
  __shared__ float lx[SS], ly_[SS], dep[SS], sc_[SS];
  __shared__ int maskv[SS];
  __shared__ float lqtab[NSTEP];
  __shared__ float encrow[USE_ENCU ? 4 : DD];

  // ---- stage gK4 into LDS (linear copy, coalesced) ----
  const float* gksrc = gK4g + (size_t)b * 16384;
  #pragma unroll
  for (int it = 0; it < 16; ++it) {
    int idx = tid + 256 * it;          // float4 index 0..4095
    *(float4*)&gK4L[idx * 4] = *(const float4*)&gksrc[idx * 4];
  }
  // ---- gV column -> registers (64 f32) ----
  float gvreg[64];
  {
    int c = tid & 127, sb = (tid >> 7) * 64;
    #pragma unroll
    for (int j = 0; j < 64; ++j)
      gvreg[j] = gVrow[((size_t)b * SS + sb + j) * DD + c];
  }
  // ---- W_out column-half -> registers (64 f32) ----
  float woreg[64];
  {
    int d = tid & 127, kb = (tid >> 7) * 64;
    #pragma unroll
    for (int j = 0; j < 64; ++j)
      woreg[j] = Wout[(size_t)(kb + j) * DD + d];
  }

  // ---- replicated state registers (identical across all threads) ----
  float r_Tm = Tmax[b], r_T0 = r_Tm;
  int r_mm = m_in[b];
  int r_start = 1, r_last = 0, city_prev = 0;
  float r_total = 0.f;
  double r_logp = 0.0;

  if (tid < SS) {
    lx[tid]  = loc[((size_t)b * SS + tid) * 2];
    ly_[tid] = loc[((size_t)b * SS + tid) * 2 + 1];
    sc_[tid] = scores[(size_t)b * SS + tid];
    maskv[tid] = (tid < 2) ? 1 : 0;
  }
  if (tid < NSTEP) lqtab[tid] = (float)log((double)(NSTEP - tid));
  __syncthreads();
  if (tid < SS) {
    float dx = __fsub_rn(lx[tid], lx[0]);
    float dy = __fsub_rn(ly_[tid], ly_[0]);
    dep[tid] = __fsqrt_rn(__fadd_rn(__fadd_rn(__fmul_rn(dx, dx), __fmul_rn(dy, dy)), 1e-12f));
  }
  float hh_r = 0.f, wtp_r = 0.f, wmp_r = 0.f, plcq_r = 0.f, encu_pref = 0.f;
  if (tid < DD) {
    hh_r = hhat[(size_t)b * DD + tid];
    wtp_r = wtp[tid]; wmp_r = wmp[tid]; plcq_r = plcq[tid];
  }

  for (int t = 0; t < NSTEP; ++t) {
    __syncthreads();                                   // B1 (state/mask boundary)
    // ---- P1: commit mask, compute query ----
    if (tid == 0 && t > 0) maskv[city_prev] = 1;
    if (!USE_ENCU) {
      if (t > 0 && tid < DD)
        encrow[tid] = enc[((size_t)b * SS + r_last) * DD + tid];
      __syncthreads();
    }
    if (tid < DD) {
      double acc = (double)hh_r + (double)r_Tm * (double)wtp_r + (double)r_mm * (double)wmp_r;
      if (t == 0) {
        acc += (double)plcq_r;
      } else if (USE_ENCU) {
        acc += (double)encu_pref;
      } else {
        double s0 = 0.0;
        for (int k = 0; k < DD; k++) s0 += (double)encrow[k] * (double)Wupd[(size_t)k * DD + tid];
        acc += s0;
      }
      qd[tid] = (double)(float)acc;
    }
    __syncthreads();                                   // B2
    // ---- P2: compat = fl32(q . gK)*0.25, masked (b128 LDS reads, q broadcast) ----
    #pragma unroll
    for (int i = 0; i < 4; ++i) {
      int p = tid + 256 * i;
      int h = p >> 7, s = p & 127;
      const double* qh = qd + h * 16;
      double c = 0.0;
      #pragma unroll
      for (int j4 = 0; j4 < 4; ++j4) {
        float4 kv = *(float4*)&gK4L[(((h * 4 + j4) * 128) + s) * 4];
        c += (double)kv.x * qh[j4 * 4 + 0] + (double)kv.y * qh[j4 * 4 + 1]
           + (double)kv.z * qh[j4 * 4 + 2] + (double)kv.w * qh[j4 * 4 + 3];
      }
      comp[h][s] = maskv[s] ? -INFINITY : __fmul_rn((float)c, 0.25f);
    }
    __syncthreads();                                   // B3
    // ---- P3: softmax per head (wave handles 2 heads) ----
    {
      int w2 = tid >> 6;
      #pragma unroll
      for (int hh2 = 0; hh2 < 2; ++hh2) {
        int h = w2 * 2 + hh2;
        float a0 = comp[h][ln], a1 = comp[h][ln + 64];
        float mx = fmaxf(a0, a1);
        #pragma unroll
        for (int off = 32; off > 0; off >>= 1) mx = fmaxf(mx, __shfl_xor(mx, off));
        float e0 = expf(__fsub_rn(a0, mx)), e1 = expf(__fsub_rn(a1, mx));
        double sm = (double)e0 + (double)e1;
        #pragma unroll
        for (int off = 32; off > 0; off >>= 1) sm += __shfl_xor(sm, off);
        float sumf = (float)sm;
        comp[h][ln]      = __fdiv_rn(e0, sumf);
        comp[h][ln + 64] = __fdiv_rn(e1, sumf);
      }
    }
    __syncthreads();                                   // B4
    // ---- P4: heads partials -> bufA pairs ----
    {
      int c = tid & 127, p = tid >> 7, h = c >> 4, sb = p * 64;
      double a0 = 0, a1 = 0, a2 = 0, a3 = 0;
      #pragma unroll
      for (int j = 0; j < 64; j += 4) {
        a0 += (double)comp[h][sb + j]     * (double)gvreg[j];
        a1 += (double)comp[h][sb + j + 1] * (double)gvreg[j + 1];
        a2 += (double)comp[h][sb + j + 2] * (double)gvreg[j + 2];
        a3 += (double)comp[h][sb + j + 3] * (double)gvreg[j + 3];
      }
      bufA[c][p] = (a0 + a1) + (a2 + a3);
    }
    __syncthreads();                                   // B5
    if (tid < DD) bufB[tid] = (double)(float)(bufA[tid][0] + bufA[tid][1]);
    __syncthreads();                                   // B6
    // ---- P5: glimpse partials -> bufC ----
    {
      int d = tid & 127, kb = (tid >> 7) * 64;
      double a0 = 0, a1 = 0, a2 = 0, a3 = 0;
      #pragma unroll
      for (int j = 0; j < 64; j += 4) {
        a0 += bufB[kb + j]     * (double)woreg[j];
        a1 += bufB[kb + j + 1] * (double)woreg[j + 1];
        a2 += bufB[kb + j + 2] * (double)woreg[j + 2];
        a3 += bufB[kb + j + 3] * (double)woreg[j + 3];
      }
      bufC[d][tid >> 7] = (a0 + a1) + (a2 + a3);
    }
    __syncthreads();                                   // B7
    if (tid < DD) bufB[tid] = (double)(float)(bufC[tid][0] + bufC[tid][1]);
    __syncthreads();                                   // B8
    // ---- P6: logits partials (logKT from global/L2, coalesced; mask-skip) ----
    {
      int s = tid & 127, p2 = tid >> 7, kb = p2 * 64;
      double r = 0.0;
      if (!maskv[s]) {
        const float* lk = lKTg + ((size_t)b * 128 + kb) * 128 + s;
        double a0 = 0, a1 = 0, a2 = 0, a3 = 0;
        #pragma unroll
        for (int j = 0; j < 64; j += 4) {
          a0 += (double)lk[(j)     * 128] * bufB[kb + j];
          a1 += (double)lk[(j + 1) * 128] * bufB[kb + j + 1];
          a2 += (double)lk[(j + 2) * 128] * bufB[kb + j + 2];
          a3 += (double)lk[(j + 3) * 128] * bufB[kb + j + 3];
        }
        r = (a0 + a1) + (a2 + a3);
      }
      bufA[s][p2] = r;
    }
    __syncthreads();                                   // B9
    // ---- P7: mega-phase, replicated per wave (no barriers, no thread0 serial) ----
    {
      double dt0 = bufA[ln][0] + bufA[ln][1];
      double dt1 = bufA[ln + 64][0] + bufA[ln + 64][1];
      int m0 = maskv[ln], m1 = maskv[ln + 64];
      float f0 = (float)dt0, f1 = (float)dt1;
      float l0 = m0 ? -INFINITY : __fmul_rn(tanhf(__fdiv_rn(f0, 11.313708498984761f)), 10.0f);
      float l1 = m1 ? -INFINITY : __fmul_rn(tanhf(__fdiv_rn(f1, 11.313708498984761f)), 10.0f);
      float mx = fmaxf(l0, l1);
      #pragma unroll
      for (int off = 32; off > 0; off >>= 1) mx = fmaxf(mx, __shfl_xor(mx, off));
      float sh0 = __fsub_rn(l0, mx), sh1 = __fsub_rn(l1, mx);
      float Lq = lqtab[t];
      float y0 = __fsub_rn(sh0, Lq), y1 = __fsub_rn(sh1, Lq);
      float yv = y0; int yi = ln;
      if (y1 > yv) { yv = y1; yi = ln + 64; }
      double e = (double)expf(sh0) + (double)expf(sh1);
      #pragma unroll
      for (int off = 32; off > 0; off >>= 1) {
        float ov = __shfl_xor(yv, off); int oi = __shfl_xor(yi, off);
        double oe = __shfl_xor(e, off);
        if (ov > yv || (ov == yv && oi < yi)) { yv = ov; yi = oi; }
        e += oe;
      }
      int city = yi;
      float a0s = __shfl(sh0, city & 63), a1s = __shfl(sh1, city & 63);
      float sh_c = (city < 64) ? a0s : a1s;
      r_logp += (double)sh_c - log(e);
      // state update 1 (exact f32, replicated)
      float dx = __fsub_rn(lx[r_last], lx[city]);
      float dy = __fsub_rn(ly_[r_last], ly_[city]);
      float d_lc = __fsqrt_rn(__fadd_rn(__fadd_rn(__fmul_rn(dx, dx), __fmul_rn(dy, dy)), 1e-12f));
      float d_cd = dep[city];
      if (r_start) d_lc = d_cd;
      int isv = (__fadd_rn(d_lc, d_cd) <= r_Tm) ? 1 : 0;
      if (isv) { r_Tm = __fsub_rn(r_Tm, d_lc); r_total = __fadd_rn(r_total, sc_[city]); }
      int startA = (isv && r_start) ? 0 : r_start;
      // all-greater (old last, old mask, new Tm); lane covers s=ln and s=ln+64
      int g0 = 1;
      if (ln >= 1) {
        float ax = __fsub_rn(lx[r_last], lx[ln]);
        float ay = __fsub_rn(ly_[r_last], ly_[ln]);
        float dlo = __fsqrt_rn(__fadd_rn(__fadd_rn(__fmul_rn(ax, ax), __fmul_rn(ay, ay)), 1e-12f));
        g0 = ((__fadd_rn(dlo, dep[ln]) > r_Tm) || m0) ? 1 : 0;
      }
      int g1;
      {
        float ax = __fsub_rn(lx[r_last], lx[ln + 64]);
        float ay = __fsub_rn(ly_[r_last], ly_[ln + 64]);
        float dlo = __fsqrt_rn(__fadd_rn(__fadd_rn(__fmul_rn(ax, ax), __fmul_rn(ay, ay)), 1e-12f));
        g1 = ((__fadd_rn(dlo, dep[ln + 64]) > r_Tm) || m1) ? 1 : 0;
      }
      int all_g = __all(g0 && g1) ? 1 : 0;
      int dbl = (all_g && (r_mm - 1 > 0)) ? 1 : 0;
      if (dbl) { r_mm -= 1; r_Tm = r_T0; }
      r_start = (startA || dbl) ? 1 : 0;
      if (isv) r_last = city;
      city_prev = city;
      if (tid == 0) out[1024 + (size_t)b * NSTEP + t] = (float)city;
      // prefetch next encU row (latency hidden across B1)
      if (USE_ENCU && t + 1 < NSTEP && tid < DD)
        encu_pref = encU[((size_t)b * SS + r_last) * DD + tid];
    }
  }
  if (tid == 0) {
    out[b] = (float)r_logp;
    out[512 + b] = r_total;
  }
}

extern "C" void kernel_launch(void* const* d_in, const int* in_sizes, int n_in,
                              void* d_out, int out_size, void* d_ws, size_t ws_size,
                              hipStream_t stream) {
  const float* enc    = (const float*)d_in[0];
  const float* loc    = (const float*)d_in[1];
  const float* scores = (const float*)d_in[2];
  const float* Tmax   = (const float*)d_in[3];
  const int*   m_in   = (const int*)d_in[4];
  const float* W_ctx  = (const float*)d_in[5];
  const float* W_upd  = (const float*)d_in[6];
  const float* W_nodes= (const float*)d_in[7];
  const float* W_out  = (const float*)d_in[8];
  const float* vtmax  = (const float*)d_in[9];
  const float* vm     = (const float*)d_in[10];
  const float* Wplc   = (const float*)d_in[11];
  float* out = (float*)d_out;
  float* ws  = (float*)d_ws;

  float* gK4   = ws;                       // 8388608 floats (33.6 MB)
  float* gVrow = gK4 + 8388608;            // 8388608
  float* lKT   = gVrow + 8388608;          // 8388608
  float* hhat  = lKT + 8388608;            // 65536
  float* wtp   = hhat + 65536;             // 128
  float* wmp   = wtp + 128;                // 128
  float* plcq  = wmp + 128;                // 128
  float* encU  = plcq + 128;               // 8388608 (33.6 MB), optional

  const size_t need_base = ((size_t)3 * 8388608 + 65536 + 384) * 4;
  const size_t need_full = need_base + (size_t)8388608 * 4;
  const bool use_encu = ws_size >= need_full;

  proj_kernel<<<dim3(1), dim3(128), 0, stream>>>(vtmax, vm, Wplc, W_upd, wtp, wmp, plcq);
  hhat_kernel<<<dim3(NB), dim3(128), 0, stream>>>(enc, W_ctx, hhat);
  gemm_kvl<<<dim3(1024, 6), dim3(256), 0, stream>>>(enc, W_nodes, gK4, gVrow, lKT);
  if (use_encu) {
    gemm64<<<dim3(1024, 2), dim3(256), 0, stream>>>(enc, W_upd, 128, encU, 128);
    decoder_kernel<true><<<dim3(NB), dim3(256), 0, stream>>>(loc, scores, Tmax, m_in, W_out, W_upd, enc,
                                                             gK4, gVrow, lKT, encU, hhat, wtp, wmp, plcq, out);
  } else {
    decoder_kernel<false><<<dim3(NB), dim3(256), 0, stream>>>(loc, scores, Tmax, m_in, W_out, W_upd, enc,
                                                              gK4, gVrow, lKT, (const float*)nullptr, hhat, wtp, wmp, plcq, out);
  }
}